// Round 1
// baseline (892.373 us; speedup 1.0000x reference)
//
#include <hip/hip_runtime.h>
#include <hip/hip_bf16.h>

typedef __attribute__((ext_vector_type(8))) short s16x8;
typedef __attribute__((ext_vector_type(4))) float f32x4;

#define MFMA(a, b, c) __builtin_amdgcn_mfma_f32_16x16x32_bf16((a), (b), (c), 0, 0, 0)

__device__ __forceinline__ short f2bf(float f) {
  unsigned u = __builtin_bit_cast(unsigned, f);
  u += 0x7FFFu + ((u >> 16) & 1u);
  return (short)(u >> 16);
}
__device__ __forceinline__ float bf2f(short s) {
  unsigned u = ((unsigned)(unsigned short)s) << 16;
  return __builtin_bit_cast(float, u);
}
__device__ __forceinline__ void async16(const void* g, void* l) {
  __builtin_amdgcn_global_load_lds((const __attribute__((address_space(1))) void*)g,
                                   (__attribute__((address_space(3))) void*)l, 16, 0, 0);
}

// ---------------- convert / transpose helpers ----------------

__global__ __launch_bounds__(256) void f32_to_bf16_k(const float* __restrict__ in,
                                                     short* __restrict__ out, int n4) {
  int i = blockIdx.x * 256 + threadIdx.x;
  if (i >= n4) return;
  float4 v = ((const float4*)in)[i];
  short4 o;
  o.x = f2bf(v.x); o.y = f2bf(v.y); o.z = f2bf(v.z); o.w = f2bf(v.w);
  ((short4*)out)[i] = o;
}

// out[n*K + k] = bf16(in[k*N + n]);  (B^T layout for GEMM)
__global__ __launch_bounds__(256) void transpose_bf16_k(const float* __restrict__ in,
                                                        short* __restrict__ out, int K, int N) {
  int idx = blockIdx.x * 256 + threadIdx.x;
  if (idx >= K * N) return;
  int n = idx / K;
  int k = idx - n * K;
  out[idx] = f2bf(in[k * N + n]);
}

// dwc weights (C,1,3,3) -> wT[tap][c]  (fp32, vector-loadable per tap)
__global__ __launch_bounds__(256) void transpose_dwc_k(const float* __restrict__ in,
                                                       float* __restrict__ out) {
  int idx = blockIdx.x * 256 + threadIdx.x;
  if (idx >= 9 * 768) return;
  int c = idx % 768;
  int tap = idx / 768;
  out[idx] = in[c * 9 + tap];
}

// ---------------- GEMM core: 128x128 tile, BK=64, bf16 MFMA ----------------
// A: (M x 768) bf16 row-major.  Bt: (Nout x 768) bf16 row-major (B transposed).
// LDS chunks XOR-swizzled: stored chunk s holds global chunk ((s&7)^((s>>3)&7)) of row s>>3.

__device__ __forceinline__ void gemm_core(const short* __restrict__ A, const short* __restrict__ Bt,
                                          short* Asm, short* Bsm, int m0, int n0,
                                          f32x4 (&acc)[4][4]) {
  const int tid = threadIdx.x;
  const int lane = tid & 63;
  const int w = tid >> 6;
  const int wm = w >> 1, wn = w & 1;
  const int l15 = lane & 15, qd = lane >> 4;

  for (int kt = 0; kt < 12; ++kt) {
    __syncthreads();
#pragma unroll
    for (int i = 0; i < 4; ++i) {
      int s = i * 256 + tid;
      int row = s >> 3, cst = s & 7;
      int cg = cst ^ (row & 7);
      async16(A + (m0 + row) * 768 + kt * 64 + cg * 8, Asm + s * 8);
      async16(Bt + (n0 + row) * 768 + kt * 64 + cg * 8, Bsm + s * 8);
    }
    __builtin_amdgcn_s_waitcnt(0x0f70);  // vmcnt(0)
    __syncthreads();
#pragma unroll
    for (int ks = 0; ks < 2; ++ks) {
      s16x8 af[4], bfr[4];
#pragma unroll
      for (int mt = 0; mt < 4; ++mt) {
        int row = wm * 64 + mt * 16 + l15;
        int kc = ks * 4 + qd;
        af[mt] = *(const s16x8*)(Asm + row * 64 + ((kc ^ (row & 7)) << 3));
      }
#pragma unroll
      for (int nt = 0; nt < 4; ++nt) {
        int row = wn * 64 + nt * 16 + l15;
        int kc = ks * 4 + qd;
        bfr[nt] = *(const s16x8*)(Bsm + row * 64 + ((kc ^ (row & 7)) << 3));
      }
#pragma unroll
      for (int mt = 0; mt < 4; ++mt)
#pragma unroll
        for (int nt = 0; nt < 4; ++nt)
          acc[mt][nt] = MFMA(af[mt], bfr[nt], acc[mt][nt]);
    }
  }
}

// GEMM1: qkv = x_bf @ Wqkv + b.  Scatter epilogue to q/k/v (B,H,197,64) bf16.
__global__ __launch_bounds__(256) void gemm_qkv(const short* __restrict__ A, const short* __restrict__ Bt,
                                                const float* __restrict__ bias,
                                                short* __restrict__ qo, short* __restrict__ ko,
                                                short* __restrict__ vo) {
  __shared__ short Asm[128 * 64];
  __shared__ short Bsm[128 * 64];
  const int m0 = blockIdx.x * 128;
  const int n0 = blockIdx.y * 128;
  const f32x4 z4 = {0.f, 0.f, 0.f, 0.f};
  f32x4 acc[4][4];
#pragma unroll
  for (int i = 0; i < 4; ++i)
#pragma unroll
    for (int j = 0; j < 4; ++j) acc[i][j] = z4;
  gemm_core(A, Bt, Asm, Bsm, m0, n0, acc);

  const int tid = threadIdx.x, lane = tid & 63, w = tid >> 6;
  const int wm = w >> 1, wn = w & 1, l15 = lane & 15, qd = lane >> 4;

  float bv[4];
  short* dstp[4];
  int coff[4];  // offset contribution of (h, d)
#pragma unroll
  for (int nt = 0; nt < 4; ++nt) {
    int n = n0 + wn * 64 + nt * 16 + l15;
    bv[nt] = bias[n];
    int s = n / 768;
    int rem = n - s * 768;
    int hh = rem >> 6, d = rem & 63;
    dstp[nt] = (s == 0) ? qo : ((s == 1) ? ko : vo);
    coff[nt] = hh * 197 * 64 + d;
  }
#pragma unroll
  for (int mt = 0; mt < 4; ++mt) {
#pragma unroll
    for (int r = 0; r < 4; ++r) {
      int m = m0 + wm * 64 + mt * 16 + qd * 4 + r;
      int bb = m / 197;
      int tok = m - bb * 197;
      size_t base = (size_t)bb * (12 * 197 * 64) + (size_t)tok * 64;
#pragma unroll
      for (int nt = 0; nt < 4; ++nt)
        dstp[nt][base + coff[nt]] = f2bf(acc[mt][nt][r] + bv[nt]);
    }
  }
}

// GEMM2: out = aout_bf @ Wproj + b, fp32 row-major output.
__global__ __launch_bounds__(256) void gemm_proj(const short* __restrict__ A, const short* __restrict__ Bt,
                                                 const float* __restrict__ bias,
                                                 float* __restrict__ out) {
  __shared__ short Asm[128 * 64];
  __shared__ short Bsm[128 * 64];
  const int m0 = blockIdx.x * 128;
  const int n0 = blockIdx.y * 128;
  const f32x4 z4 = {0.f, 0.f, 0.f, 0.f};
  f32x4 acc[4][4];
#pragma unroll
  for (int i = 0; i < 4; ++i)
#pragma unroll
    for (int j = 0; j < 4; ++j) acc[i][j] = z4;
  gemm_core(A, Bt, Asm, Bsm, m0, n0, acc);

  const int tid = threadIdx.x, lane = tid & 63, w = tid >> 6;
  const int wm = w >> 1, wn = w & 1, l15 = lane & 15, qd = lane >> 4;
#pragma unroll
  for (int mt = 0; mt < 4; ++mt) {
#pragma unroll
    for (int r = 0; r < 4; ++r) {
      int m = m0 + wm * 64 + mt * 16 + qd * 4 + r;
      float* orow = out + (size_t)m * 768;
#pragma unroll
      for (int nt = 0; nt < 4; ++nt) {
        int n = n0 + wn * 64 + nt * 16 + l15;
        orow[n] = acc[mt][nt][r] + bias[n];
      }
    }
  }
}

// ---------------- fused attention (conv moved to its own kernel) ----------------
// 1 WG = (b,h). K in LDS [197][64] swizzled; V^T in LDS [64][256] swizzled (keys 197..223 zeroed);
// per-wave P chunk [16][40] for C-layout -> A-layout transpose.
__global__ __launch_bounds__(256) void attn_fused(const short* __restrict__ qa, const short* __restrict__ ka,
                                                  const short* __restrict__ va,
                                                  short* __restrict__ aout) {
  __shared__ short Klds[197 * 64];
  __shared__ short Vt[64 * 256];
  __shared__ short Plds[4][16 * 40];

  const int tid = threadIdx.x;
  const int lane = tid & 63;
  const int w = tid >> 6;
  const int l15 = lane & 15, qd = lane >> 4;
  const int bh = blockIdx.x;
  const int b = bh / 12;
  const int h = bh - b * 12;
  const short* kb = ka + (size_t)bh * (197 * 64);
  const short* vb = va + (size_t)bh * (197 * 64);
  const short* qb = qa + (size_t)bh * (197 * 64);

  // stage K (swizzled chunks)
  for (int c = tid; c < 197 * 8; c += 256) {
    int row = c >> 3, cc = c & 7;
    s16x8 v8 = *(const s16x8*)(kb + row * 64 + cc * 8);
    *(s16x8*)(Klds + row * 64 + ((cc ^ (row & 7)) << 3)) = v8;
  }
  // stage V transposed (Vt[d][key], swizzled along key-chunks)
  for (int c = tid; c < 197 * 8; c += 256) {
    int key = c >> 3, cc = c & 7;
    s16x8 v8 = *(const s16x8*)(vb + key * 64 + cc * 8);
    int kc = key >> 3, km = key & 7;
#pragma unroll
    for (int j = 0; j < 8; ++j) {
      int d = cc * 8 + j;
      Vt[d * 256 + ((kc ^ (d & 7)) << 3) + km] = v8[j];
    }
  }
  // zero Vt pad keys 197..223
  for (int i = tid; i < 64 * 27; i += 256) {
    int d = i / 27;
    int key = 197 + (i - d * 27);
    Vt[d * 256 + (((key >> 3) ^ (d & 7)) << 3) + (key & 7)] = 0;
  }
  __syncthreads();

  for (int qt = w; qt < 13; qt += 4) {
    const int m0 = qt * 16;
    int mrow = m0 + l15; if (mrow > 196) mrow = 196;
    s16x8 qf0 = *(const s16x8*)(qb + mrow * 64 + qd * 8);
    s16x8 qf1 = *(const s16x8*)(qb + mrow * 64 + 32 + qd * 8);

    // S = Q K^T  (13 key tiles of 16)
    f32x4 S[13];
#pragma unroll
    for (int kt = 0; kt < 13; ++kt) {
      int krow = kt * 16 + l15; if (krow > 196) krow = 196;
      s16x8 kf0 = *(const s16x8*)(Klds + krow * 64 + ((qd ^ (krow & 7)) << 3));
      s16x8 kf1 = *(const s16x8*)(Klds + krow * 64 + (((4 + qd) ^ (krow & 7)) << 3));
      f32x4 sa = {0.f, 0.f, 0.f, 0.f};
      sa = MFMA(qf0, kf0, sa);
      sa = MFMA(qf1, kf1, sa);
      S[kt] = sa;
    }
    // scale + mask invalid keys (cols 197..207 live in tile 12 at l15>4)
    const bool maskme = (l15 > 4);
#pragma unroll
    for (int kt = 0; kt < 13; ++kt) {
#pragma unroll
      for (int r = 0; r < 4; ++r) {
        float sv = S[kt][r] * 0.125f;
        if (kt == 12 && maskme) sv = -1e30f;
        S[kt][r] = sv;
      }
    }
    // softmax over 197 keys: row r lives in the 16 lanes sharing qd
    float li[4];
#pragma unroll
    for (int r = 0; r < 4; ++r) {
      float m = S[0][r];
#pragma unroll
      for (int kt = 1; kt < 13; ++kt) m = fmaxf(m, S[kt][r]);
#pragma unroll
      for (int off = 1; off < 16; off <<= 1) m = fmaxf(m, __shfl_xor(m, off));
      float l = 0.f;
#pragma unroll
      for (int kt = 0; kt < 13; ++kt) {
        float p = __builtin_amdgcn_exp2f((S[kt][r] - m) * 1.44269504f);
        S[kt][r] = p;
        l += p;
      }
#pragma unroll
      for (int off = 1; off < 16; off <<= 1) l += __shfl_xor(l, off);
      li[r] = l;
    }

    // O = P V   (P: C-layout -> LDS -> A-layout, 7 chunks of K=32)
    const f32x4 z4 = {0.f, 0.f, 0.f, 0.f};
    f32x4 O[4] = {z4, z4, z4, z4};
    short* Pw = &Plds[w][0];
#pragma unroll
    for (int kt2 = 0; kt2 < 7; ++kt2) {
#pragma unroll
      for (int sub = 0; sub < 2; ++sub) {
        const int ktile = kt2 * 2 + sub;
#pragma unroll
        for (int r = 0; r < 4; ++r) {
          short pv = 0;
          if (ktile < 13) pv = f2bf(S[ktile][r]);
          Pw[(qd * 4 + r) * 40 + sub * 16 + l15] = pv;
        }
      }
      __builtin_amdgcn_s_waitcnt(0xc07f);  // lgkmcnt(0)
      s16x8 pf = *(const s16x8*)(Pw + l15 * 40 + qd * 8);
#pragma unroll
      for (int nt = 0; nt < 4; ++nt) {
        int d = nt * 16 + l15;
        s16x8 vf = *(const s16x8*)(Vt + d * 256 + (((kt2 * 4 + qd) ^ (d & 7)) << 3));
        O[nt] = MFMA(pf, vf, O[nt]);
      }
    }

    // epilogue: 1/l scale, store bf16 (B,N,C)
#pragma unroll
    for (int r = 0; r < 4; ++r) {
      int tok = m0 + qd * 4 + r;
      if (tok > 196) continue;
      float linv = __builtin_amdgcn_rcpf(li[r]);
      size_t ob = ((size_t)b * 197 + tok) * 768 + h * 64;
#pragma unroll
      for (int nt = 0; nt < 4; ++nt) {
        int d = nt * 16 + l15;
        aout[ob + d] = f2bf(O[nt][r] * linv);
      }
    }
  }
}

// ---------------- depthwise conv 3x3 on V, added into aout (bf16 RMW) ----------------
// one thread = one (b, p, 8-channel chunk); fully coalesced 16B accesses.
__global__ __launch_bounds__(256) void dwconv_add_k(const short* __restrict__ va,
                                                    const float* __restrict__ wT,
                                                    const float* __restrict__ dwcb,
                                                    short* __restrict__ aout) {
  int idx = blockIdx.x * 256 + threadIdx.x;
  if (idx >= 256 * 196 * 96) return;
  int ch = idx % 96;
  int rest = idx / 96;
  int p = rest % 196;
  int b = rest / 196;
  int y = p / 14, x = p - y * 14;
  int c0 = ch * 8;
  int h = c0 >> 6, d0 = c0 & 63;
  const short* vrow = va + (size_t)(b * 12 + h) * (197 * 64) + d0;

  float acc[8];
  float4 b0 = *(const float4*)(dwcb + c0);
  float4 b1 = *(const float4*)(dwcb + c0 + 4);
  acc[0] = b0.x; acc[1] = b0.y; acc[2] = b0.z; acc[3] = b0.w;
  acc[4] = b1.x; acc[5] = b1.y; acc[6] = b1.z; acc[7] = b1.w;

#pragma unroll
  for (int dy = -1; dy <= 1; ++dy) {
    int yy = y + dy;
    if (yy < 0 || yy > 13) continue;
#pragma unroll
    for (int dx = -1; dx <= 1; ++dx) {
      int xx = x + dx;
      if (xx < 0 || xx > 13) continue;
      int key = 1 + yy * 14 + xx;
      s16x8 v8 = *(const s16x8*)(vrow + (size_t)key * 64);
      int tap = (dy + 1) * 3 + (dx + 1);
      const float* wrow = wT + tap * 768 + c0;
      float4 w0 = *(const float4*)(wrow);
      float4 w1 = *(const float4*)(wrow + 4);
      acc[0] += w0.x * bf2f(v8[0]);
      acc[1] += w0.y * bf2f(v8[1]);
      acc[2] += w0.z * bf2f(v8[2]);
      acc[3] += w0.w * bf2f(v8[3]);
      acc[4] += w1.x * bf2f(v8[4]);
      acc[5] += w1.y * bf2f(v8[5]);
      acc[6] += w1.z * bf2f(v8[6]);
      acc[7] += w1.w * bf2f(v8[7]);
    }
  }

  size_t ao = ((size_t)b * 197 + (1 + p)) * 768 + c0;
  s16x8 a8 = *(const s16x8*)(aout + ao);
  s16x8 o8;
#pragma unroll
  for (int j = 0; j < 8; ++j) o8[j] = f2bf(bf2f(a8[j]) + acc[j]);
  *(s16x8*)(aout + ao) = o8;
}

// ---------------- launch ----------------

extern "C" void kernel_launch(void* const* d_in, const int* in_sizes, int n_in,
                              void* d_out, int out_size, void* d_ws, size_t ws_size,
                              hipStream_t stream) {
  const float* x     = (const float*)d_in[0];
  const float* Wqkv  = (const float*)d_in[1];
  const float* bqkv  = (const float*)d_in[2];
  const float* Wproj = (const float*)d_in[3];
  const float* bproj = (const float*)d_in[4];
  const float* dwcw  = (const float*)d_in[5];
  const float* dwcb  = (const float*)d_in[6];
  float* out = (float*)d_out;

  const size_t XE = (size_t)50432 * 768;  // 38,731,776 elems
  short* ws     = (short*)d_ws;
  short* xbf    = ws;
  short* wqkvT  = xbf + XE;
  short* wprojT = wqkvT + (size_t)2304 * 768;
  short* qarr   = wprojT + (size_t)768 * 768;
  short* karr   = qarr + XE;
  short* varr   = karr + XE;
  short* aoutb  = xbf;               // reuse x_bf space (dead after gemm_qkv)
  float* wT     = (float*)wqkvT;     // reuse Wqkv^T space (dead after gemm_qkv)

  f32_to_bf16_k<<<(int)((XE / 4 + 255) / 256), 256, 0, stream>>>(x, xbf, (int)(XE / 4));
  transpose_bf16_k<<<(2304 * 768 + 255) / 256, 256, 0, stream>>>(Wqkv, wqkvT, 768, 2304);
  transpose_bf16_k<<<(768 * 768 + 255) / 256, 256, 0, stream>>>(Wproj, wprojT, 768, 768);
  gemm_qkv<<<dim3(394, 18), 256, 0, stream>>>(xbf, wqkvT, bqkv, qarr, karr, varr);
  transpose_dwc_k<<<27, 256, 0, stream>>>(dwcw, wT);
  attn_fused<<<3072, 256, 0, stream>>>(qarr, karr, varr, aoutb);
  dwconv_add_k<<<(256 * 196 * 96) / 256, 256, 0, stream>>>(varr, wT, dwcb, aoutb);
  gemm_proj<<<dim3(394, 6), 256, 0, stream>>>(aoutb, wprojT, bproj, out);
}

// Round 2
// 890.135 us; speedup vs baseline: 1.0025x; 1.0025x over previous
//
#include <hip/hip_runtime.h>
#include <hip/hip_bf16.h>

typedef __attribute__((ext_vector_type(8))) short s16x8;
typedef __attribute__((ext_vector_type(4))) float f32x4;

#define MFMA(a, b, c) __builtin_amdgcn_mfma_f32_16x16x32_bf16((a), (b), (c), 0, 0, 0)

__device__ __forceinline__ short f2bf(float f) {
  unsigned u = __builtin_bit_cast(unsigned, f);
  u += 0x7FFFu + ((u >> 16) & 1u);
  return (short)(u >> 16);
}
__device__ __forceinline__ float bf2f(short s) {
  unsigned u = ((unsigned)(unsigned short)s) << 16;
  return __builtin_bit_cast(float, u);
}
__device__ __forceinline__ void async16(const void* g, void* l) {
  __builtin_amdgcn_global_load_lds((const __attribute__((address_space(1))) void*)g,
                                   (__attribute__((address_space(3))) void*)l, 16, 0, 0);
}

// ---------------- convert / transpose helpers ----------------

__global__ __launch_bounds__(256) void f32_to_bf16_k(const float* __restrict__ in,
                                                     short* __restrict__ out, int n4) {
  int i = blockIdx.x * 256 + threadIdx.x;
  if (i >= n4) return;
  float4 v = ((const float4*)in)[i];
  short4 o;
  o.x = f2bf(v.x); o.y = f2bf(v.y); o.z = f2bf(v.z); o.w = f2bf(v.w);
  ((short4*)out)[i] = o;
}

// out[n*K + k] = bf16(in[k*N + n]);  (B^T layout for GEMM)
__global__ __launch_bounds__(256) void transpose_bf16_k(const float* __restrict__ in,
                                                        short* __restrict__ out, int K, int N) {
  int idx = blockIdx.x * 256 + threadIdx.x;
  if (idx >= K * N) return;
  int n = idx / K;
  int k = idx - n * K;
  out[idx] = f2bf(in[k * N + n]);
}

// dwc weights (C,1,3,3) -> wT[tap][c]  (fp32, vector-loadable per tap)
__global__ __launch_bounds__(256) void transpose_dwc_k(const float* __restrict__ in,
                                                       float* __restrict__ out) {
  int idx = blockIdx.x * 256 + threadIdx.x;
  if (idx >= 9 * 768) return;
  int c = idx % 768;
  int tap = idx / 768;
  out[idx] = in[c * 9 + tap];
}

// ---------------- GEMM core: 128x128 tile, BK=64, bf16 MFMA ----------------
// A: (M x 768) bf16 row-major.  Bt: (Nout x 768) bf16 row-major (B transposed).
// LDS chunks XOR-swizzled: stored chunk s holds global chunk ((s&7)^((s>>3)&7)) of row s>>3.

__device__ __forceinline__ void gemm_core(const short* __restrict__ A, const short* __restrict__ Bt,
                                          short* Asm, short* Bsm, int m0, int n0,
                                          f32x4 (&acc)[4][4]) {
  const int tid = threadIdx.x;
  const int lane = tid & 63;
  const int w = tid >> 6;
  const int wm = w >> 1, wn = w & 1;
  const int l15 = lane & 15, qd = lane >> 4;

  for (int kt = 0; kt < 12; ++kt) {
    __syncthreads();
#pragma unroll
    for (int i = 0; i < 4; ++i) {
      int s = i * 256 + tid;
      int row = s >> 3, cst = s & 7;
      int cg = cst ^ (row & 7);
      async16(A + (m0 + row) * 768 + kt * 64 + cg * 8, Asm + s * 8);
      async16(Bt + (n0 + row) * 768 + kt * 64 + cg * 8, Bsm + s * 8);
    }
    __builtin_amdgcn_s_waitcnt(0x0f70);  // vmcnt(0)
    __syncthreads();
#pragma unroll
    for (int ks = 0; ks < 2; ++ks) {
      s16x8 af[4], bfr[4];
#pragma unroll
      for (int mt = 0; mt < 4; ++mt) {
        int row = wm * 64 + mt * 16 + l15;
        int kc = ks * 4 + qd;
        af[mt] = *(const s16x8*)(Asm + row * 64 + ((kc ^ (row & 7)) << 3));
      }
#pragma unroll
      for (int nt = 0; nt < 4; ++nt) {
        int row = wn * 64 + nt * 16 + l15;
        int kc = ks * 4 + qd;
        bfr[nt] = *(const s16x8*)(Bsm + row * 64 + ((kc ^ (row & 7)) << 3));
      }
#pragma unroll
      for (int mt = 0; mt < 4; ++mt)
#pragma unroll
        for (int nt = 0; nt < 4; ++nt)
          acc[mt][nt] = MFMA(af[mt], bfr[nt], acc[mt][nt]);
    }
  }
}

// XCD-bijective remap (m204): orig dispatch id -> contiguous wgid per XCD.
// With n-tile fastest inside each m-tile group, the NT blocks sharing an
// A-panel run consecutively on ONE XCD -> A-tile lives in that XCD's L2.
__device__ __forceinline__ int xcd_remap(int orig, int nwg) {
  int xcd = orig & 7;
  int grp = orig >> 3;
  int q = nwg >> 3, r = nwg & 7;
  return (xcd < r ? xcd * (q + 1) : r * (q + 1) + (xcd - r) * q) + grp;
}

// GEMM1: qkv = x_bf @ Wqkv + b.  Scatter epilogue to q/k/v (B,H,197,64) bf16.
__global__ __launch_bounds__(256) void gemm_qkv(const short* __restrict__ A, const short* __restrict__ Bt,
                                                const float* __restrict__ bias,
                                                short* __restrict__ qo, short* __restrict__ ko,
                                                short* __restrict__ vo) {
  __shared__ short Asm[128 * 64];
  __shared__ short Bsm[128 * 64];
  const int nwg = 394 * 18;
  int wgid = xcd_remap(blockIdx.x, nwg);
  int mt0 = wgid / 18;
  int nt0 = wgid - mt0 * 18;
  const int m0 = mt0 * 128;
  const int n0 = nt0 * 128;
  const f32x4 z4 = {0.f, 0.f, 0.f, 0.f};
  f32x4 acc[4][4];
#pragma unroll
  for (int i = 0; i < 4; ++i)
#pragma unroll
    for (int j = 0; j < 4; ++j) acc[i][j] = z4;
  gemm_core(A, Bt, Asm, Bsm, m0, n0, acc);

  const int tid = threadIdx.x, lane = tid & 63, w = tid >> 6;
  const int wm = w >> 1, wn = w & 1, l15 = lane & 15, qd = lane >> 4;

  float bv[4];
  short* dstp[4];
  int coff[4];  // offset contribution of (h, d)
#pragma unroll
  for (int nt = 0; nt < 4; ++nt) {
    int n = n0 + wn * 64 + nt * 16 + l15;
    bv[nt] = bias[n];
    int s = n / 768;
    int rem = n - s * 768;
    int hh = rem >> 6, d = rem & 63;
    dstp[nt] = (s == 0) ? qo : ((s == 1) ? ko : vo);
    coff[nt] = hh * 197 * 64 + d;
  }
#pragma unroll
  for (int mt = 0; mt < 4; ++mt) {
#pragma unroll
    for (int r = 0; r < 4; ++r) {
      int m = m0 + wm * 64 + mt * 16 + qd * 4 + r;
      int bb = m / 197;
      int tok = m - bb * 197;
      size_t base = (size_t)bb * (12 * 197 * 64) + (size_t)tok * 64;
#pragma unroll
      for (int nt = 0; nt < 4; ++nt)
        dstp[nt][base + coff[nt]] = f2bf(acc[mt][nt][r] + bv[nt]);
    }
  }
}

// GEMM2: out = aout_bf @ Wproj + b, fp32 row-major output.
__global__ __launch_bounds__(256) void gemm_proj(const short* __restrict__ A, const short* __restrict__ Bt,
                                                 const float* __restrict__ bias,
                                                 float* __restrict__ out) {
  __shared__ short Asm[128 * 64];
  __shared__ short Bsm[128 * 64];
  const int nwg = 394 * 6;
  int wgid = xcd_remap(blockIdx.x, nwg);
  int mt0 = wgid / 6;
  int nt0 = wgid - mt0 * 6;
  const int m0 = mt0 * 128;
  const int n0 = nt0 * 128;
  const f32x4 z4 = {0.f, 0.f, 0.f, 0.f};
  f32x4 acc[4][4];
#pragma unroll
  for (int i = 0; i < 4; ++i)
#pragma unroll
    for (int j = 0; j < 4; ++j) acc[i][j] = z4;
  gemm_core(A, Bt, Asm, Bsm, m0, n0, acc);

  const int tid = threadIdx.x, lane = tid & 63, w = tid >> 6;
  const int wm = w >> 1, wn = w & 1, l15 = lane & 15, qd = lane >> 4;
#pragma unroll
  for (int mt = 0; mt < 4; ++mt) {
#pragma unroll
    for (int r = 0; r < 4; ++r) {
      int m = m0 + wm * 64 + mt * 16 + qd * 4 + r;
      float* orow = out + (size_t)m * 768;
#pragma unroll
      for (int nt = 0; nt < 4; ++nt) {
        int n = n0 + wn * 64 + nt * 16 + l15;
        orow[n] = acc[mt][nt][r] + bias[n];
      }
    }
  }
}

// ---------------- fused attention (conv in its own kernel) ----------------
// 1 WG = (b,h). K in LDS [197][64] swizzled; V^T in LDS [64][256] swizzled (keys 197..223 zeroed);
// per-wave P chunk [16][40] for C-layout -> A-layout transpose.
__global__ __launch_bounds__(256) void attn_fused(const short* __restrict__ qa, const short* __restrict__ ka,
                                                  const short* __restrict__ va,
                                                  short* __restrict__ aout) {
  __shared__ short Klds[197 * 64];
  __shared__ short Vt[64 * 256];
  __shared__ short Plds[4][16 * 40];

  const int tid = threadIdx.x;
  const int lane = tid & 63;
  const int w = tid >> 6;
  const int l15 = lane & 15, qd = lane >> 4;
  const int bh = blockIdx.x;
  const int b = bh / 12;
  const int h = bh - b * 12;
  const short* kb = ka + (size_t)bh * (197 * 64);
  const short* vb = va + (size_t)bh * (197 * 64);
  const short* qb = qa + (size_t)bh * (197 * 64);

  // stage K (swizzled chunks)
  for (int c = tid; c < 197 * 8; c += 256) {
    int row = c >> 3, cc = c & 7;
    s16x8 v8 = *(const s16x8*)(kb + row * 64 + cc * 8);
    *(s16x8*)(Klds + row * 64 + ((cc ^ (row & 7)) << 3)) = v8;
  }
  // stage V transposed (Vt[d][key], swizzled along key-chunks)
  for (int c = tid; c < 197 * 8; c += 256) {
    int key = c >> 3, cc = c & 7;
    s16x8 v8 = *(const s16x8*)(vb + key * 64 + cc * 8);
    int kc = key >> 3, km = key & 7;
#pragma unroll
    for (int j = 0; j < 8; ++j) {
      int d = cc * 8 + j;
      Vt[d * 256 + ((kc ^ (d & 7)) << 3) + km] = v8[j];
    }
  }
  // zero Vt pad keys 197..223
  for (int i = tid; i < 64 * 27; i += 256) {
    int d = i / 27;
    int key = 197 + (i - d * 27);
    Vt[d * 256 + (((key >> 3) ^ (d & 7)) << 3) + (key & 7)] = 0;
  }
  __syncthreads();

  for (int qt = w; qt < 13; qt += 4) {
    const int m0 = qt * 16;
    int mrow = m0 + l15; if (mrow > 196) mrow = 196;
    s16x8 qf0 = *(const s16x8*)(qb + mrow * 64 + qd * 8);
    s16x8 qf1 = *(const s16x8*)(qb + mrow * 64 + 32 + qd * 8);

    // S = Q K^T  (13 key tiles of 16)
    f32x4 S[13];
#pragma unroll
    for (int kt = 0; kt < 13; ++kt) {
      int krow = kt * 16 + l15; if (krow > 196) krow = 196;
      s16x8 kf0 = *(const s16x8*)(Klds + krow * 64 + ((qd ^ (krow & 7)) << 3));
      s16x8 kf1 = *(const s16x8*)(Klds + krow * 64 + (((4 + qd) ^ (krow & 7)) << 3));
      f32x4 sa = {0.f, 0.f, 0.f, 0.f};
      sa = MFMA(qf0, kf0, sa);
      sa = MFMA(qf1, kf1, sa);
      S[kt] = sa;
    }
    // scale + mask invalid keys (cols 197..207 live in tile 12 at l15>4)
    const bool maskme = (l15 > 4);
#pragma unroll
    for (int kt = 0; kt < 13; ++kt) {
#pragma unroll
      for (int r = 0; r < 4; ++r) {
        float sv = S[kt][r] * 0.125f;
        if (kt == 12 && maskme) sv = -1e30f;
        S[kt][r] = sv;
      }
    }
    // softmax over 197 keys: row r lives in the 16 lanes sharing qd
    float li[4];
#pragma unroll
    for (int r = 0; r < 4; ++r) {
      float m = S[0][r];
#pragma unroll
      for (int kt = 1; kt < 13; ++kt) m = fmaxf(m, S[kt][r]);
#pragma unroll
      for (int off = 1; off < 16; off <<= 1) m = fmaxf(m, __shfl_xor(m, off));
      float l = 0.f;
#pragma unroll
      for (int kt = 0; kt < 13; ++kt) {
        float p = __builtin_amdgcn_exp2f((S[kt][r] - m) * 1.44269504f);
        S[kt][r] = p;
        l += p;
      }
#pragma unroll
      for (int off = 1; off < 16; off <<= 1) l += __shfl_xor(l, off);
      li[r] = l;
    }

    // O = P V   (P: C-layout -> LDS -> A-layout, 7 chunks of K=32)
    const f32x4 z4 = {0.f, 0.f, 0.f, 0.f};
    f32x4 O[4] = {z4, z4, z4, z4};
    short* Pw = &Plds[w][0];
#pragma unroll
    for (int kt2 = 0; kt2 < 7; ++kt2) {
#pragma unroll
      for (int sub = 0; sub < 2; ++sub) {
        const int ktile = kt2 * 2 + sub;
#pragma unroll
        for (int r = 0; r < 4; ++r) {
          short pv = 0;
          if (ktile < 13) pv = f2bf(S[ktile][r]);
          Pw[(qd * 4 + r) * 40 + sub * 16 + l15] = pv;
        }
      }
      __builtin_amdgcn_s_waitcnt(0xc07f);  // lgkmcnt(0)
      s16x8 pf = *(const s16x8*)(Pw + l15 * 40 + qd * 8);
#pragma unroll
      for (int nt = 0; nt < 4; ++nt) {
        int d = nt * 16 + l15;
        s16x8 vf = *(const s16x8*)(Vt + d * 256 + (((kt2 * 4 + qd) ^ (d & 7)) << 3));
        O[nt] = MFMA(pf, vf, O[nt]);
      }
    }

    // epilogue: 1/l scale, store bf16 (B,N,C)
#pragma unroll
    for (int r = 0; r < 4; ++r) {
      int tok = m0 + qd * 4 + r;
      if (tok > 196) continue;
      float linv = __builtin_amdgcn_rcpf(li[r]);
      size_t ob = ((size_t)b * 197 + tok) * 768 + h * 64;
#pragma unroll
      for (int nt = 0; nt < 4; ++nt) {
        int d = nt * 16 + l15;
        aout[ob + d] = f2bf(O[nt][r] * linv);
      }
    }
  }
}

// ---------------- depthwise conv 3x3 on V, added into aout (bf16 RMW) ----------------
// one thread = one (b, p, 8-channel chunk); fully coalesced 16B accesses.
__global__ __launch_bounds__(256) void dwconv_add_k(const short* __restrict__ va,
                                                    const float* __restrict__ wT,
                                                    const float* __restrict__ dwcb,
                                                    short* __restrict__ aout) {
  int idx = blockIdx.x * 256 + threadIdx.x;
  if (idx >= 256 * 196 * 96) return;
  int ch = idx % 96;
  int rest = idx / 96;
  int p = rest % 196;
  int b = rest / 196;
  int y = p / 14, x = p - y * 14;
  int c0 = ch * 8;
  int h = c0 >> 6, d0 = c0 & 63;
  const short* vrow = va + (size_t)(b * 12 + h) * (197 * 64) + d0;

  float acc[8];
  float4 b0 = *(const float4*)(dwcb + c0);
  float4 b1 = *(const float4*)(dwcb + c0 + 4);
  acc[0] = b0.x; acc[1] = b0.y; acc[2] = b0.z; acc[3] = b0.w;
  acc[4] = b1.x; acc[5] = b1.y; acc[6] = b1.z; acc[7] = b1.w;

#pragma unroll
  for (int dy = -1; dy <= 1; ++dy) {
    int yy = y + dy;
    if (yy < 0 || yy > 13) continue;
#pragma unroll
    for (int dx = -1; dx <= 1; ++dx) {
      int xx = x + dx;
      if (xx < 0 || xx > 13) continue;
      int key = 1 + yy * 14 + xx;
      s16x8 v8 = *(const s16x8*)(vrow + (size_t)key * 64);
      int tap = (dy + 1) * 3 + (dx + 1);
      const float* wrow = wT + tap * 768 + c0;
      float4 w0 = *(const float4*)(wrow);
      float4 w1 = *(const float4*)(wrow + 4);
      acc[0] += w0.x * bf2f(v8[0]);
      acc[1] += w0.y * bf2f(v8[1]);
      acc[2] += w0.z * bf2f(v8[2]);
      acc[3] += w0.w * bf2f(v8[3]);
      acc[4] += w1.x * bf2f(v8[4]);
      acc[5] += w1.y * bf2f(v8[5]);
      acc[6] += w1.z * bf2f(v8[6]);
      acc[7] += w1.w * bf2f(v8[7]);
    }
  }

  size_t ao = ((size_t)b * 197 + (1 + p)) * 768 + c0;
  s16x8 a8 = *(const s16x8*)(aout + ao);
  s16x8 o8;
#pragma unroll
  for (int j = 0; j < 8; ++j) o8[j] = f2bf(bf2f(a8[j]) + acc[j]);
  *(s16x8*)(aout + ao) = o8;
}

// ---------------- launch ----------------

extern "C" void kernel_launch(void* const* d_in, const int* in_sizes, int n_in,
                              void* d_out, int out_size, void* d_ws, size_t ws_size,
                              hipStream_t stream) {
  const float* x     = (const float*)d_in[0];
  const float* Wqkv  = (const float*)d_in[1];
  const float* bqkv  = (const float*)d_in[2];
  const float* Wproj = (const float*)d_in[3];
  const float* bproj = (const float*)d_in[4];
  const float* dwcw  = (const float*)d_in[5];
  const float* dwcb  = (const float*)d_in[6];
  float* out = (float*)d_out;

  const size_t XE = (size_t)50432 * 768;  // 38,731,776 elems
  short* ws     = (short*)d_ws;
  short* xbf    = ws;
  short* wqkvT  = xbf + XE;
  short* wprojT = wqkvT + (size_t)2304 * 768;
  short* qarr   = wprojT + (size_t)768 * 768;
  short* karr   = qarr + XE;
  short* varr   = karr + XE;
  short* aoutb  = xbf;               // reuse x_bf space (dead after gemm_qkv)
  float* wT     = (float*)wqkvT;     // reuse Wqkv^T space (dead after gemm_qkv)

  f32_to_bf16_k<<<(int)((XE / 4 + 255) / 256), 256, 0, stream>>>(x, xbf, (int)(XE / 4));
  transpose_bf16_k<<<(2304 * 768 + 255) / 256, 256, 0, stream>>>(Wqkv, wqkvT, 768, 2304);
  transpose_bf16_k<<<(768 * 768 + 255) / 256, 256, 0, stream>>>(Wproj, wprojT, 768, 768);
  gemm_qkv<<<394 * 18, 256, 0, stream>>>(xbf, wqkvT, bqkv, qarr, karr, varr);
  transpose_dwc_k<<<27, 256, 0, stream>>>(dwcw, wT);
  attn_fused<<<3072, 256, 0, stream>>>(qarr, karr, varr, aoutb);
  dwconv_add_k<<<(256 * 196 * 96) / 256, 256, 0, stream>>>(varr, wT, dwcb, aoutb);
  gemm_proj<<<394 * 6, 256, 0, stream>>>(aoutb, wprojT, bproj, out);
}

// Round 3
// 840.016 us; speedup vs baseline: 1.0623x; 1.0597x over previous
//
#include <hip/hip_runtime.h>
#include <hip/hip_bf16.h>

typedef __attribute__((ext_vector_type(8))) short s16x8;
typedef __attribute__((ext_vector_type(4))) float f32x4;

#define MFMA(a, b, c) __builtin_amdgcn_mfma_f32_16x16x32_bf16((a), (b), (c), 0, 0, 0)

__device__ __forceinline__ short f2bf(float f) {
  unsigned u = __builtin_bit_cast(unsigned, f);
  u += 0x7FFFu + ((u >> 16) & 1u);
  return (short)(u >> 16);
}
__device__ __forceinline__ float bf2f(short s) {
  unsigned u = ((unsigned)(unsigned short)s) << 16;
  return __builtin_bit_cast(float, u);
}
__device__ __forceinline__ void async16(const void* g, void* l) {
  __builtin_amdgcn_global_load_lds((const __attribute__((address_space(1))) void*)g,
                                   (__attribute__((address_space(3))) void*)l, 16, 0, 0);
}

// ---------------- convert / transpose helpers ----------------

__global__ __launch_bounds__(256) void f32_to_bf16_k(const float* __restrict__ in,
                                                     short* __restrict__ out, int n4) {
  int i = blockIdx.x * 256 + threadIdx.x;
  if (i >= n4) return;
  float4 v = ((const float4*)in)[i];
  short4 o;
  o.x = f2bf(v.x); o.y = f2bf(v.y); o.z = f2bf(v.z); o.w = f2bf(v.w);
  ((short4*)out)[i] = o;
}

// out[n*K + k] = bf16(in[k*N + n]);  (B^T layout for GEMM)
__global__ __launch_bounds__(256) void transpose_bf16_k(const float* __restrict__ in,
                                                        short* __restrict__ out, int K, int N) {
  int idx = blockIdx.x * 256 + threadIdx.x;
  if (idx >= K * N) return;
  int n = idx / K;
  int k = idx - n * K;
  out[idx] = f2bf(in[k * N + n]);
}

// dwc weights (C,1,3,3) -> wT[tap][c]  (fp32, vector-loadable per tap)
__global__ __launch_bounds__(256) void transpose_dwc_k(const float* __restrict__ in,
                                                       float* __restrict__ out) {
  int idx = blockIdx.x * 256 + threadIdx.x;
  if (idx >= 9 * 768) return;
  int c = idx % 768;
  int tap = idx / 768;
  out[idx] = in[c * 9 + tap];
}

// XCD-bijective remap (m204): orig dispatch id -> contiguous wgid per XCD.
__device__ __forceinline__ int xcd_remap(int orig, int nwg) {
  int xcd = orig & 7;
  int grp = orig >> 3;
  int q = nwg >> 3, r = nwg & 7;
  return (xcd < r ? xcd * (q + 1) : r * (q + 1) + (xcd - r) * q) + grp;
}

// ---------------- GEMM core v2: 256x256 tile, BK=32, ring-4 LDS, counted vmcnt ----
// A: (M x 768) bf16 row-major.  Bt: (Nout x 768) bf16 row-major.
// 512 threads = 8 waves (2 M-rows x 4 N-cols), per-wave 128x64 output, acc[8][4].
// LDS: Asm[4][256][32], Bsm[4][256][32] bf16 (ring of 4 K-tiles, 128 KiB total).
// Swizzle: 16B chunk c of row stored at c ^ (row & 3)  (4 chunks per 64B row).
// Pipeline: stage K-tile t+3, wait vmcnt(12) [tile t landed, t+1..t+3 in flight],
// raw s_barrier (NO __syncthreads -> no vmcnt(0) drain), ds_read+MFMA, s_barrier.

__device__ __forceinline__ void gemm256_core(const short* __restrict__ A,
                                             const short* __restrict__ Bt,
                                             short* Asm, short* Bsm,
                                             int m0, int n0, f32x4 (&acc)[8][4]) {
  const int tid = threadIdx.x;
  const int lane = tid & 63;
  const int w = tid >> 6;
  const int wm = w >> 2, wn = w & 3;
  const int l15 = lane & 15, qd = lane >> 4;
  const int arow0 = wm * 128, bcol0 = wn * 64;

  auto STAGE = [&](int t) {
    const int slot = t & 3;
    short* As = Asm + slot * 8192;
    short* Bs = Bsm + slot * 8192;
#pragma unroll
    for (int j = 0; j < 2; ++j) {
      int s = j * 512 + tid;
      int row = s >> 2, cst = s & 3;
      int cg = cst ^ (row & 3);
      async16(A + (size_t)(m0 + row) * 768 + t * 32 + cg * 8, As + s * 8);
      async16(Bt + (size_t)(n0 + row) * 768 + t * 32 + cg * 8, Bs + s * 8);
    }
  };

  auto COMPUTE = [&](int t) {
    const int slot = t & 3;
    const short* As = Asm + slot * 8192;
    const short* Bs = Bsm + slot * 8192;
    s16x8 af[8], bfr[4];
#pragma unroll
    for (int mt = 0; mt < 8; ++mt) {
      int row = arow0 + mt * 16 + l15;
      af[mt] = *(const s16x8*)(As + row * 32 + ((qd ^ (row & 3)) << 3));
    }
#pragma unroll
    for (int nt = 0; nt < 4; ++nt) {
      int row = bcol0 + nt * 16 + l15;
      bfr[nt] = *(const s16x8*)(Bs + row * 32 + ((qd ^ (row & 3)) << 3));
    }
    __builtin_amdgcn_s_setprio(1);
#pragma unroll
    for (int mt = 0; mt < 8; ++mt)
#pragma unroll
      for (int nt = 0; nt < 4; ++nt)
        acc[mt][nt] = MFMA(af[mt], bfr[nt], acc[mt][nt]);
    __builtin_amdgcn_s_setprio(0);
  };

  // prologue: stage tiles 0,1,2 in strict order (vmcnt ledger depends on it)
  STAGE(0);
  __builtin_amdgcn_sched_barrier(0);
  STAGE(1);
  __builtin_amdgcn_sched_barrier(0);
  STAGE(2);
  __builtin_amdgcn_sched_barrier(0);

  // main loop: K = 768 = 24 tiles of 32; t = 0..20 stage t+3
  for (int t = 0; t < 21; ++t) {
    STAGE(t + 3);
    __builtin_amdgcn_sched_barrier(0);
    __builtin_amdgcn_s_waitcnt(0x0f7c);  // vmcnt(12): tile t landed, 12 in flight
    __builtin_amdgcn_s_barrier();
    __builtin_amdgcn_sched_barrier(0);
    COMPUTE(t);
    __builtin_amdgcn_sched_barrier(0);
    __builtin_amdgcn_s_barrier();        // readers of slot t&3 done -> next STAGE may overwrite
    __builtin_amdgcn_sched_barrier(0);
  }
  // epilogue: drain 8 -> 4 -> 0
  __builtin_amdgcn_s_waitcnt(0x0f78);    // vmcnt(8): tile 21 landed
  __builtin_amdgcn_s_barrier();
  __builtin_amdgcn_sched_barrier(0);
  COMPUTE(21);
  __builtin_amdgcn_s_barrier();
  __builtin_amdgcn_s_waitcnt(0x0f74);    // vmcnt(4): tile 22 landed
  __builtin_amdgcn_s_barrier();
  __builtin_amdgcn_sched_barrier(0);
  COMPUTE(22);
  __builtin_amdgcn_s_barrier();
  __builtin_amdgcn_s_waitcnt(0x0f70);    // vmcnt(0): tile 23 landed
  __builtin_amdgcn_s_barrier();
  __builtin_amdgcn_sched_barrier(0);
  COMPUTE(23);
}

// GEMM1: qkv = x_bf @ Wqkv + b.  Scatter epilogue to q/k/v (B,H,197,64) bf16.
__global__ __launch_bounds__(512, 2) void gemm_qkv256(const short* __restrict__ A,
                                                      const short* __restrict__ Bt,
                                                      const float* __restrict__ bias,
                                                      short* __restrict__ qo, short* __restrict__ ko,
                                                      short* __restrict__ vo) {
  extern __shared__ short smem[];
  const int nwg = 197 * 9;
  int wgid = xcd_remap(blockIdx.x, nwg);
  int mt0 = wgid / 9;
  int nt0 = wgid - mt0 * 9;
  const int m0 = mt0 * 256;
  const int n0 = nt0 * 256;
  const f32x4 z4 = {0.f, 0.f, 0.f, 0.f};
  f32x4 acc[8][4];
#pragma unroll
  for (int i = 0; i < 8; ++i)
#pragma unroll
    for (int j = 0; j < 4; ++j) acc[i][j] = z4;
  gemm256_core(A, Bt, smem, smem + 32768, m0, n0, acc);

  const int tid = threadIdx.x, lane = tid & 63, w = tid >> 6;
  const int wm = w >> 2, wn = w & 3, l15 = lane & 15, qd = lane >> 4;

  float bv[4];
  short* dstp[4];
  int coff[4];
#pragma unroll
  for (int nt = 0; nt < 4; ++nt) {
    int n = n0 + wn * 64 + nt * 16 + l15;
    bv[nt] = bias[n];
    int s = n / 768;
    int rem = n - s * 768;
    int hh = rem >> 6, d = rem & 63;
    dstp[nt] = (s == 0) ? qo : ((s == 1) ? ko : vo);
    coff[nt] = hh * 197 * 64 + d;
  }
#pragma unroll
  for (int mt = 0; mt < 8; ++mt) {
#pragma unroll
    for (int r = 0; r < 4; ++r) {
      int m = m0 + wm * 128 + mt * 16 + qd * 4 + r;
      int bb = m / 197;
      int tok = m - bb * 197;
      size_t base = (size_t)bb * (12 * 197 * 64) + (size_t)tok * 64;
#pragma unroll
      for (int nt = 0; nt < 4; ++nt)
        dstp[nt][base + coff[nt]] = f2bf(acc[mt][nt][r] + bv[nt]);
    }
  }
}

// GEMM2: out = aout_bf @ Wproj + b, fp32 row-major output.
__global__ __launch_bounds__(512, 2) void gemm_proj256(const short* __restrict__ A,
                                                       const short* __restrict__ Bt,
                                                       const float* __restrict__ bias,
                                                       float* __restrict__ out) {
  extern __shared__ short smem[];
  const int nwg = 197 * 3;
  int wgid = xcd_remap(blockIdx.x, nwg);
  int mt0 = wgid / 3;
  int nt0 = wgid - mt0 * 3;
  const int m0 = mt0 * 256;
  const int n0 = nt0 * 256;
  const f32x4 z4 = {0.f, 0.f, 0.f, 0.f};
  f32x4 acc[8][4];
#pragma unroll
  for (int i = 0; i < 8; ++i)
#pragma unroll
    for (int j = 0; j < 4; ++j) acc[i][j] = z4;
  gemm256_core(A, Bt, smem, smem + 32768, m0, n0, acc);

  const int tid = threadIdx.x, lane = tid & 63, w = tid >> 6;
  const int wm = w >> 2, wn = w & 3, l15 = lane & 15, qd = lane >> 4;
#pragma unroll
  for (int mt = 0; mt < 8; ++mt) {
#pragma unroll
    for (int r = 0; r < 4; ++r) {
      int m = m0 + wm * 128 + mt * 16 + qd * 4 + r;
      float* orow = out + (size_t)m * 768;
#pragma unroll
      for (int nt = 0; nt < 4; ++nt) {
        int n = n0 + wn * 64 + nt * 16 + l15;
        orow[n] = acc[mt][nt][r] + bias[n];
      }
    }
  }
}

// ---------------- fused attention (conv in its own kernel) ----------------
__global__ __launch_bounds__(256) void attn_fused(const short* __restrict__ qa, const short* __restrict__ ka,
                                                  const short* __restrict__ va,
                                                  short* __restrict__ aout) {
  __shared__ short Klds[197 * 64];
  __shared__ short Vt[64 * 256];
  __shared__ short Plds[4][16 * 40];

  const int tid = threadIdx.x;
  const int lane = tid & 63;
  const int w = tid >> 6;
  const int l15 = lane & 15, qd = lane >> 4;
  const int bh = blockIdx.x;
  const int b = bh / 12;
  const short* kb = ka + (size_t)bh * (197 * 64);
  const short* vb = va + (size_t)bh * (197 * 64);
  const short* qb = qa + (size_t)bh * (197 * 64);
  const int h = bh - b * 12;

  for (int c = tid; c < 197 * 8; c += 256) {
    int row = c >> 3, cc = c & 7;
    s16x8 v8 = *(const s16x8*)(kb + row * 64 + cc * 8);
    *(s16x8*)(Klds + row * 64 + ((cc ^ (row & 7)) << 3)) = v8;
  }
  for (int c = tid; c < 197 * 8; c += 256) {
    int key = c >> 3, cc = c & 7;
    s16x8 v8 = *(const s16x8*)(vb + key * 64 + cc * 8);
    int kc = key >> 3, km = key & 7;
#pragma unroll
    for (int j = 0; j < 8; ++j) {
      int d = cc * 8 + j;
      Vt[d * 256 + ((kc ^ (d & 7)) << 3) + km] = v8[j];
    }
  }
  for (int i = tid; i < 64 * 27; i += 256) {
    int d = i / 27;
    int key = 197 + (i - d * 27);
    Vt[d * 256 + (((key >> 3) ^ (d & 7)) << 3) + (key & 7)] = 0;
  }
  __syncthreads();

  for (int qt = w; qt < 13; qt += 4) {
    const int m0 = qt * 16;
    int mrow = m0 + l15; if (mrow > 196) mrow = 196;
    s16x8 qf0 = *(const s16x8*)(qb + mrow * 64 + qd * 8);
    s16x8 qf1 = *(const s16x8*)(qb + mrow * 64 + 32 + qd * 8);

    f32x4 S[13];
#pragma unroll
    for (int kt = 0; kt < 13; ++kt) {
      int krow = kt * 16 + l15; if (krow > 196) krow = 196;
      s16x8 kf0 = *(const s16x8*)(Klds + krow * 64 + ((qd ^ (krow & 7)) << 3));
      s16x8 kf1 = *(const s16x8*)(Klds + krow * 64 + (((4 + qd) ^ (krow & 7)) << 3));
      f32x4 sa = {0.f, 0.f, 0.f, 0.f};
      sa = MFMA(qf0, kf0, sa);
      sa = MFMA(qf1, kf1, sa);
      S[kt] = sa;
    }
    const bool maskme = (l15 > 4);
#pragma unroll
    for (int kt = 0; kt < 13; ++kt) {
#pragma unroll
      for (int r = 0; r < 4; ++r) {
        float sv = S[kt][r] * 0.125f;
        if (kt == 12 && maskme) sv = -1e30f;
        S[kt][r] = sv;
      }
    }
    float li[4];
#pragma unroll
    for (int r = 0; r < 4; ++r) {
      float m = S[0][r];
#pragma unroll
      for (int kt = 1; kt < 13; ++kt) m = fmaxf(m, S[kt][r]);
#pragma unroll
      for (int off = 1; off < 16; off <<= 1) m = fmaxf(m, __shfl_xor(m, off));
      float l = 0.f;
#pragma unroll
      for (int kt = 0; kt < 13; ++kt) {
        float p = __builtin_amdgcn_exp2f((S[kt][r] - m) * 1.44269504f);
        S[kt][r] = p;
        l += p;
      }
#pragma unroll
      for (int off = 1; off < 16; off <<= 1) l += __shfl_xor(l, off);
      li[r] = l;
    }

    const f32x4 z4 = {0.f, 0.f, 0.f, 0.f};
    f32x4 O[4] = {z4, z4, z4, z4};
    short* Pw = &Plds[w][0];
#pragma unroll
    for (int kt2 = 0; kt2 < 7; ++kt2) {
#pragma unroll
      for (int sub = 0; sub < 2; ++sub) {
        const int ktile = kt2 * 2 + sub;
#pragma unroll
        for (int r = 0; r < 4; ++r) {
          short pv = 0;
          if (ktile < 13) pv = f2bf(S[ktile][r]);
          Pw[(qd * 4 + r) * 40 + sub * 16 + l15] = pv;
        }
      }
      __builtin_amdgcn_s_waitcnt(0xc07f);  // lgkmcnt(0)
      s16x8 pf = *(const s16x8*)(Pw + l15 * 40 + qd * 8);
#pragma unroll
      for (int nt = 0; nt < 4; ++nt) {
        int d = nt * 16 + l15;
        s16x8 vf = *(const s16x8*)(Vt + d * 256 + (((kt2 * 4 + qd) ^ (d & 7)) << 3));
        O[nt] = MFMA(pf, vf, O[nt]);
      }
    }

#pragma unroll
    for (int r = 0; r < 4; ++r) {
      int tok = m0 + qd * 4 + r;
      if (tok > 196) continue;
      float linv = __builtin_amdgcn_rcpf(li[r]);
      size_t ob = ((size_t)b * 197 + tok) * 768 + h * 64;
#pragma unroll
      for (int nt = 0; nt < 4; ++nt) {
        int d = nt * 16 + l15;
        aout[ob + d] = f2bf(O[nt][r] * linv);
      }
    }
  }
}

// ---------------- depthwise conv 3x3 on V, added into aout (bf16 RMW) ----------------
__global__ __launch_bounds__(256) void dwconv_add_k(const short* __restrict__ va,
                                                    const float* __restrict__ wT,
                                                    const float* __restrict__ dwcb,
                                                    short* __restrict__ aout) {
  int idx = blockIdx.x * 256 + threadIdx.x;
  if (idx >= 256 * 196 * 96) return;
  int ch = idx % 96;
  int rest = idx / 96;
  int p = rest % 196;
  int b = rest / 196;
  int y = p / 14, x = p - y * 14;
  int c0 = ch * 8;
  int h = c0 >> 6, d0 = c0 & 63;
  const short* vrow = va + (size_t)(b * 12 + h) * (197 * 64) + d0;

  float acc[8];
  float4 b0 = *(const float4*)(dwcb + c0);
  float4 b1 = *(const float4*)(dwcb + c0 + 4);
  acc[0] = b0.x; acc[1] = b0.y; acc[2] = b0.z; acc[3] = b0.w;
  acc[4] = b1.x; acc[5] = b1.y; acc[6] = b1.z; acc[7] = b1.w;

#pragma unroll
  for (int dy = -1; dy <= 1; ++dy) {
    int yy = y + dy;
    if (yy < 0 || yy > 13) continue;
#pragma unroll
    for (int dx = -1; dx <= 1; ++dx) {
      int xx = x + dx;
      if (xx < 0 || xx > 13) continue;
      int key = 1 + yy * 14 + xx;
      s16x8 v8 = *(const s16x8*)(vrow + (size_t)key * 64);
      int tap = (dy + 1) * 3 + (dx + 1);
      const float* wrow = wT + tap * 768 + c0;
      float4 w0 = *(const float4*)(wrow);
      float4 w1 = *(const float4*)(wrow + 4);
      acc[0] += w0.x * bf2f(v8[0]);
      acc[1] += w0.y * bf2f(v8[1]);
      acc[2] += w0.z * bf2f(v8[2]);
      acc[3] += w0.w * bf2f(v8[3]);
      acc[4] += w1.x * bf2f(v8[4]);
      acc[5] += w1.y * bf2f(v8[5]);
      acc[6] += w1.z * bf2f(v8[6]);
      acc[7] += w1.w * bf2f(v8[7]);
    }
  }

  size_t ao = ((size_t)b * 197 + (1 + p)) * 768 + c0;
  s16x8 a8 = *(const s16x8*)(aout + ao);
  s16x8 o8;
#pragma unroll
  for (int j = 0; j < 8; ++j) o8[j] = f2bf(bf2f(a8[j]) + acc[j]);
  *(s16x8*)(aout + ao) = o8;
}

// ---------------- launch ----------------

extern "C" void kernel_launch(void* const* d_in, const int* in_sizes, int n_in,
                              void* d_out, int out_size, void* d_ws, size_t ws_size,
                              hipStream_t stream) {
  const float* x     = (const float*)d_in[0];
  const float* Wqkv  = (const float*)d_in[1];
  const float* bqkv  = (const float*)d_in[2];
  const float* Wproj = (const float*)d_in[3];
  const float* bproj = (const float*)d_in[4];
  const float* dwcw  = (const float*)d_in[5];
  const float* dwcb  = (const float*)d_in[6];
  float* out = (float*)d_out;

  const size_t XE = (size_t)50432 * 768;  // 38,731,776 elems
  short* ws     = (short*)d_ws;
  short* xbf    = ws;
  short* wqkvT  = xbf + XE;
  short* wprojT = wqkvT + (size_t)2304 * 768;
  short* qarr   = wprojT + (size_t)768 * 768;
  short* karr   = qarr + XE;
  short* varr   = karr + XE;
  short* aoutb  = xbf;               // reuse x_bf space (dead after gemm_qkv)
  float* wT     = (float*)wqkvT;     // reuse Wqkv^T space (dead after gemm_qkv)

  static bool attr_set = false;
  if (!attr_set) {
    hipFuncSetAttribute((const void*)gemm_qkv256, hipFuncAttributeMaxDynamicSharedMemorySize, 131072);
    hipFuncSetAttribute((const void*)gemm_proj256, hipFuncAttributeMaxDynamicSharedMemorySize, 131072);
    attr_set = true;
  }

  f32_to_bf16_k<<<(int)((XE / 4 + 255) / 256), 256, 0, stream>>>(x, xbf, (int)(XE / 4));
  transpose_bf16_k<<<(2304 * 768 + 255) / 256, 256, 0, stream>>>(Wqkv, wqkvT, 768, 2304);
  transpose_bf16_k<<<(768 * 768 + 255) / 256, 256, 0, stream>>>(Wproj, wprojT, 768, 768);
  gemm_qkv256<<<197 * 9, 512, 131072, stream>>>(xbf, wqkvT, bqkv, qarr, karr, varr);
  transpose_dwc_k<<<27, 256, 0, stream>>>(dwcw, wT);
  attn_fused<<<3072, 256, 0, stream>>>(qarr, karr, varr, aoutb);
  dwconv_add_k<<<(256 * 196 * 96) / 256, 256, 0, stream>>>(varr, wT, dwcb, aoutb);
  gemm_proj256<<<197 * 3, 512, 131072, stream>>>(aoutb, wprojT, bproj, out);
}

// Round 5
// 829.937 us; speedup vs baseline: 1.0752x; 1.0121x over previous
//
#include <hip/hip_runtime.h>
#include <hip/hip_bf16.h>

typedef __attribute__((ext_vector_type(8))) short s16x8;
typedef __attribute__((ext_vector_type(4))) float f32x4;

#define MFMA(a, b, c) __builtin_amdgcn_mfma_f32_16x16x32_bf16((a), (b), (c), 0, 0, 0)

__device__ __forceinline__ short f2bf(float f) {
  unsigned u = __builtin_bit_cast(unsigned, f);
  u += 0x7FFFu + ((u >> 16) & 1u);
  return (short)(u >> 16);
}
__device__ __forceinline__ float bf2f(short s) {
  unsigned u = ((unsigned)(unsigned short)s) << 16;
  return __builtin_bit_cast(float, u);
}
__device__ __forceinline__ void async16(const void* g, void* l) {
  __builtin_amdgcn_global_load_lds((const __attribute__((address_space(1))) void*)g,
                                   (__attribute__((address_space(3))) void*)l, 16, 0, 0);
}

// ---------------- convert / transpose helpers ----------------

__global__ __launch_bounds__(256) void f32_to_bf16_k(const float* __restrict__ in,
                                                     short* __restrict__ out, int n4) {
  int i = blockIdx.x * 256 + threadIdx.x;
  if (i >= n4) return;
  float4 v = ((const float4*)in)[i];
  short4 o;
  o.x = f2bf(v.x); o.y = f2bf(v.y); o.z = f2bf(v.z); o.w = f2bf(v.w);
  ((short4*)out)[i] = o;
}

// out[n*K + k] = bf16(in[k*N + n]);  (B^T layout for GEMM)
__global__ __launch_bounds__(256) void transpose_bf16_k(const float* __restrict__ in,
                                                        short* __restrict__ out, int K, int N) {
  int idx = blockIdx.x * 256 + threadIdx.x;
  if (idx >= K * N) return;
  int n = idx / K;
  int k = idx - n * K;
  out[idx] = f2bf(in[k * N + n]);
}

// dwc weights (C,1,3,3) -> wT[tap][c]  (fp32, vector-loadable per tap)
__global__ __launch_bounds__(256) void transpose_dwc_k(const float* __restrict__ in,
                                                       float* __restrict__ out) {
  int idx = blockIdx.x * 256 + threadIdx.x;
  if (idx >= 9 * 768) return;
  int c = idx % 768;
  int tap = idx / 768;
  out[idx] = in[c * 9 + tap];
}

// XCD-bijective remap (m204): orig dispatch id -> contiguous wgid per XCD.
__device__ __forceinline__ int xcd_remap(int orig, int nwg) {
  int xcd = orig & 7;
  int grp = orig >> 3;
  int q = nwg >> 3, r = nwg & 7;
  return (xcd < r ? xcd * (q + 1) : r * (q + 1) + (xcd - r) * q) + grp;
}

// ---------------- GEMM core v2: 256x256 tile, BK=32, ring-4 LDS, counted vmcnt ----
// A: (M x 768) bf16 row-major.  Bt: (Nout x 768) bf16 row-major.
// 512 threads = 8 waves (2 M-rows x 4 N-cols), per-wave 128x64 output, acc[8][4].
// LDS: Asm[4][256][32], Bsm[4][256][32] bf16 (ring of 4 K-tiles, 128 KiB total).
// Swizzle: 16B chunk c of row stored at slot c ^ ((row>>1)&3).
//   (row stride = 64B = 16 banks, period-2 in bank halves; keying the XOR on
//    row>>1 spreads the 8 same-parity rows of a 16-lane read phase across all
//    4 chunk slots -> 2 lanes/bank at 2 addrs = free (m136). row&3 keying gave
//    4-way conflicts = the 16.3M SQ_LDS_BANK_CONFLICT seen in round 3.)
// Pipeline: stage K-tile t+3, wait vmcnt(12) [tile t landed, t+1..t+3 in flight],
// raw s_barrier (NO __syncthreads -> no vmcnt(0) drain), ds_read+MFMA, s_barrier.

__device__ __forceinline__ void gemm256_core(const short* __restrict__ A,
                                             const short* __restrict__ Bt,
                                             short* Asm, short* Bsm,
                                             int m0, int n0, f32x4 (&acc)[8][4]) {
  const int tid = threadIdx.x;
  const int lane = tid & 63;
  const int w = tid >> 6;
  const int wm = w >> 2, wn = w & 3;
  const int l15 = lane & 15, qd = lane >> 4;
  const int arow0 = wm * 128, bcol0 = wn * 64;

  auto STAGE = [&](int t) {
    const int slot = t & 3;
    short* As = Asm + slot * 8192;
    short* Bs = Bsm + slot * 8192;
#pragma unroll
    for (int j = 0; j < 2; ++j) {
      int s = j * 512 + tid;
      int row = s >> 2, cst = s & 3;
      int cg = cst ^ ((row >> 1) & 3);
      async16(A + (size_t)(m0 + row) * 768 + t * 32 + cg * 8, As + s * 8);
      async16(Bt + (size_t)(n0 + row) * 768 + t * 32 + cg * 8, Bs + s * 8);
    }
  };

  auto COMPUTE = [&](int t) {
    const int slot = t & 3;
    const short* As = Asm + slot * 8192;
    const short* Bs = Bsm + slot * 8192;
    s16x8 af[8], bfr[4];
#pragma unroll
    for (int mt = 0; mt < 8; ++mt) {
      int row = arow0 + mt * 16 + l15;
      af[mt] = *(const s16x8*)(As + row * 32 + ((qd ^ ((row >> 1) & 3)) << 3));
    }
#pragma unroll
    for (int nt = 0; nt < 4; ++nt) {
      int row = bcol0 + nt * 16 + l15;
      bfr[nt] = *(const s16x8*)(Bs + row * 32 + ((qd ^ ((row >> 1) & 3)) << 3));
    }
    __builtin_amdgcn_s_setprio(1);
#pragma unroll
    for (int mt = 0; mt < 8; ++mt)
#pragma unroll
      for (int nt = 0; nt < 4; ++nt)
        acc[mt][nt] = MFMA(af[mt], bfr[nt], acc[mt][nt]);
    __builtin_amdgcn_s_setprio(0);
  };

  // prologue: stage tiles 0,1,2 in strict order (vmcnt ledger depends on it)
  STAGE(0);
  __builtin_amdgcn_sched_barrier(0);
  STAGE(1);
  __builtin_amdgcn_sched_barrier(0);
  STAGE(2);
  __builtin_amdgcn_sched_barrier(0);

  // main loop: K = 768 = 24 tiles of 32; t = 0..20 stage t+3
  for (int t = 0; t < 21; ++t) {
    STAGE(t + 3);
    __builtin_amdgcn_sched_barrier(0);
    __builtin_amdgcn_s_waitcnt(0x0f7c);  // vmcnt(12): tile t landed, 12 in flight
    __builtin_amdgcn_s_barrier();
    __builtin_amdgcn_sched_barrier(0);
    COMPUTE(t);
    __builtin_amdgcn_sched_barrier(0);
    __builtin_amdgcn_s_barrier();        // readers of slot t&3 done -> next STAGE may overwrite
    __builtin_amdgcn_sched_barrier(0);
  }
  // epilogue: drain 8 -> 4 -> 0
  __builtin_amdgcn_s_waitcnt(0x0f78);    // vmcnt(8): tile 21 landed
  __builtin_amdgcn_s_barrier();
  __builtin_amdgcn_sched_barrier(0);
  COMPUTE(21);
  __builtin_amdgcn_s_barrier();
  __builtin_amdgcn_s_waitcnt(0x0f74);    // vmcnt(4): tile 22 landed
  __builtin_amdgcn_s_barrier();
  __builtin_amdgcn_sched_barrier(0);
  COMPUTE(22);
  __builtin_amdgcn_s_barrier();
  __builtin_amdgcn_s_waitcnt(0x0f70);    // vmcnt(0): tile 23 landed
  __builtin_amdgcn_s_barrier();
  __builtin_amdgcn_sched_barrier(0);
  COMPUTE(23);
}

// GEMM1: qkv = x_bf @ Wqkv + b.  Scatter epilogue to q/k/v (B,H,197,64) bf16.
__global__ __launch_bounds__(512, 2) void gemm_qkv256(const short* __restrict__ A,
                                                      const short* __restrict__ Bt,
                                                      const float* __restrict__ bias,
                                                      short* __restrict__ qo, short* __restrict__ ko,
                                                      short* __restrict__ vo) {
  extern __shared__ short smem[];
  const int nwg = 197 * 9;
  int wgid = xcd_remap(blockIdx.x, nwg);
  int mt0 = wgid / 9;
  int nt0 = wgid - mt0 * 9;
  const int m0 = mt0 * 256;
  const int n0 = nt0 * 256;
  const f32x4 z4 = {0.f, 0.f, 0.f, 0.f};
  f32x4 acc[8][4];
#pragma unroll
  for (int i = 0; i < 8; ++i)
#pragma unroll
    for (int j = 0; j < 4; ++j) acc[i][j] = z4;
  gemm256_core(A, Bt, smem, smem + 32768, m0, n0, acc);

  const int tid = threadIdx.x, lane = tid & 63, w = tid >> 6;
  const int wm = w >> 2, wn = w & 3, l15 = lane & 15, qd = lane >> 4;

  float bv[4];
  short* dstp[4];
  int coff[4];
#pragma unroll
  for (int nt = 0; nt < 4; ++nt) {
    int n = n0 + wn * 64 + nt * 16 + l15;
    bv[nt] = bias[n];
    int s = n / 768;
    int rem = n - s * 768;
    int hh = rem >> 6, d = rem & 63;
    dstp[nt] = (s == 0) ? qo : ((s == 1) ? ko : vo);
    coff[nt] = hh * 197 * 64 + d;
  }
#pragma unroll
  for (int mt = 0; mt < 8; ++mt) {
#pragma unroll
    for (int r = 0; r < 4; ++r) {
      int m = m0 + wm * 128 + mt * 16 + qd * 4 + r;
      int bb = m / 197;
      int tok = m - bb * 197;
      size_t base = (size_t)bb * (12 * 197 * 64) + (size_t)tok * 64;
#pragma unroll
      for (int nt = 0; nt < 4; ++nt)
        dstp[nt][base + coff[nt]] = f2bf(acc[mt][nt][r] + bv[nt]);
    }
  }
}

// GEMM2: out = aout_bf @ Wproj + b, fp32 row-major output.
__global__ __launch_bounds__(512, 2) void gemm_proj256(const short* __restrict__ A,
                                                       const short* __restrict__ Bt,
                                                       const float* __restrict__ bias,
                                                       float* __restrict__ out) {
  extern __shared__ short smem[];
  const int nwg = 197 * 3;
  int wgid = xcd_remap(blockIdx.x, nwg);
  int mt0 = wgid / 3;
  int nt0 = wgid - mt0 * 3;
  const int m0 = mt0 * 256;
  const int n0 = nt0 * 256;
  const f32x4 z4 = {0.f, 0.f, 0.f, 0.f};
  f32x4 acc[8][4];
#pragma unroll
  for (int i = 0; i < 8; ++i)
#pragma unroll
    for (int j = 0; j < 4; ++j) acc[i][j] = z4;
  gemm256_core(A, Bt, smem, smem + 32768, m0, n0, acc);

  const int tid = threadIdx.x, lane = tid & 63, w = tid >> 6;
  const int wm = w >> 2, wn = w & 3, l15 = lane & 15, qd = lane >> 4;
#pragma unroll
  for (int mt = 0; mt < 8; ++mt) {
#pragma unroll
    for (int r = 0; r < 4; ++r) {
      int m = m0 + wm * 128 + mt * 16 + qd * 4 + r;
      float* orow = out + (size_t)m * 768;
#pragma unroll
      for (int nt = 0; nt < 4; ++nt) {
        int n = n0 + wn * 64 + nt * 16 + l15;
        orow[n] = acc[mt][nt][r] + bias[n];
      }
    }
  }
}

// ---------------- fused attention (conv in its own kernel) ----------------
__global__ __launch_bounds__(256) void attn_fused(const short* __restrict__ qa, const short* __restrict__ ka,
                                                  const short* __restrict__ va,
                                                  short* __restrict__ aout) {
  __shared__ short Klds[197 * 64];
  __shared__ short Vt[64 * 256];
  __shared__ short Plds[4][16 * 40];

  const int tid = threadIdx.x;
  const int lane = tid & 63;
  const int w = tid >> 6;
  const int l15 = lane & 15, qd = lane >> 4;
  const int bh = blockIdx.x;
  const int b = bh / 12;
  const short* kb = ka + (size_t)bh * (197 * 64);
  const short* vb = va + (size_t)bh * (197 * 64);
  const short* qb = qa + (size_t)bh * (197 * 64);
  const int h = bh - b * 12;

  for (int c = tid; c < 197 * 8; c += 256) {
    int row = c >> 3, cc = c & 7;
    s16x8 v8 = *(const s16x8*)(kb + row * 64 + cc * 8);
    *(s16x8*)(Klds + row * 64 + ((cc ^ (row & 7)) << 3)) = v8;
  }
  for (int c = tid; c < 197 * 8; c += 256) {
    int key = c >> 3, cc = c & 7;
    s16x8 v8 = *(const s16x8*)(vb + key * 64 + cc * 8);
    int kc = key >> 3, km = key & 7;
#pragma unroll
    for (int j = 0; j < 8; ++j) {
      int d = cc * 8 + j;
      Vt[d * 256 + ((kc ^ (d & 7)) << 3) + km] = v8[j];
    }
  }
  for (int i = tid; i < 64 * 27; i += 256) {
    int d = i / 27;
    int key = 197 + (i - d * 27);
    Vt[d * 256 + (((key >> 3) ^ (d & 7)) << 3) + (key & 7)] = 0;
  }
  __syncthreads();

  for (int qt = w; qt < 13; qt += 4) {
    const int m0 = qt * 16;
    int mrow = m0 + l15; if (mrow > 196) mrow = 196;
    s16x8 qf0 = *(const s16x8*)(qb + mrow * 64 + qd * 8);
    s16x8 qf1 = *(const s16x8*)(qb + mrow * 64 + 32 + qd * 8);

    f32x4 S[13];
#pragma unroll
    for (int kt = 0; kt < 13; ++kt) {
      int krow = kt * 16 + l15; if (krow > 196) krow = 196;
      s16x8 kf0 = *(const s16x8*)(Klds + krow * 64 + ((qd ^ (krow & 7)) << 3));
      s16x8 kf1 = *(const s16x8*)(Klds + krow * 64 + (((4 + qd) ^ (krow & 7)) << 3));
      f32x4 sa = {0.f, 0.f, 0.f, 0.f};
      sa = MFMA(qf0, kf0, sa);
      sa = MFMA(qf1, kf1, sa);
      S[kt] = sa;
    }
    const bool maskme = (l15 > 4);
#pragma unroll
    for (int kt = 0; kt < 13; ++kt) {
#pragma unroll
      for (int r = 0; r < 4; ++r) {
        float sv = S[kt][r] * 0.125f;
        if (kt == 12 && maskme) sv = -1e30f;
        S[kt][r] = sv;
      }
    }
    float li[4];
#pragma unroll
    for (int r = 0; r < 4; ++r) {
      float m = S[0][r];
#pragma unroll
      for (int kt = 1; kt < 13; ++kt) m = fmaxf(m, S[kt][r]);
#pragma unroll
      for (int off = 1; off < 16; off <<= 1) m = fmaxf(m, __shfl_xor(m, off));
      float l = 0.f;
#pragma unroll
      for (int kt = 0; kt < 13; ++kt) {
        float p = __builtin_amdgcn_exp2f((S[kt][r] - m) * 1.44269504f);
        S[kt][r] = p;
        l += p;
      }
#pragma unroll
      for (int off = 1; off < 16; off <<= 1) l += __shfl_xor(l, off);
      li[r] = l;
    }

    const f32x4 z4 = {0.f, 0.f, 0.f, 0.f};
    f32x4 O[4] = {z4, z4, z4, z4};
    short* Pw = &Plds[w][0];
#pragma unroll
    for (int kt2 = 0; kt2 < 7; ++kt2) {
#pragma unroll
      for (int sub = 0; sub < 2; ++sub) {
        const int ktile = kt2 * 2 + sub;
#pragma unroll
        for (int r = 0; r < 4; ++r) {
          short pv = 0;
          if (ktile < 13) pv = f2bf(S[ktile][r]);
          Pw[(qd * 4 + r) * 40 + sub * 16 + l15] = pv;
        }
      }
      __builtin_amdgcn_s_waitcnt(0xc07f);  // lgkmcnt(0)
      s16x8 pf = *(const s16x8*)(Pw + l15 * 40 + qd * 8);
#pragma unroll
      for (int nt = 0; nt < 4; ++nt) {
        int d = nt * 16 + l15;
        s16x8 vf = *(const s16x8*)(Vt + d * 256 + (((kt2 * 4 + qd) ^ (d & 7)) << 3));
        O[nt] = MFMA(pf, vf, O[nt]);
      }
    }

#pragma unroll
    for (int r = 0; r < 4; ++r) {
      int tok = m0 + qd * 4 + r;
      if (tok > 196) continue;
      float linv = __builtin_amdgcn_rcpf(li[r]);
      size_t ob = ((size_t)b * 197 + tok) * 768 + h * 64;
#pragma unroll
      for (int nt = 0; nt < 4; ++nt) {
        int d = nt * 16 + l15;
        aout[ob + d] = f2bf(O[nt][r] * linv);
      }
    }
  }
}

// ---------------- depthwise conv 3x3 on V, added into aout (bf16 RMW) ----------------
__global__ __launch_bounds__(256) void dwconv_add_k(const short* __restrict__ va,
                                                    const float* __restrict__ wT,
                                                    const float* __restrict__ dwcb,
                                                    short* __restrict__ aout) {
  int idx = blockIdx.x * 256 + threadIdx.x;
  if (idx >= 256 * 196 * 96) return;
  int ch = idx % 96;
  int rest = idx / 96;
  int p = rest % 196;
  int b = rest / 196;
  int y = p / 14, x = p - y * 14;
  int c0 = ch * 8;
  int h = c0 >> 6, d0 = c0 & 63;
  const short* vrow = va + (size_t)(b * 12 + h) * (197 * 64) + d0;

  float acc[8];
  float4 b0 = *(const float4*)(dwcb + c0);
  float4 b1 = *(const float4*)(dwcb + c0 + 4);
  acc[0] = b0.x; acc[1] = b0.y; acc[2] = b0.z; acc[3] = b0.w;
  acc[4] = b1.x; acc[5] = b1.y; acc[6] = b1.z; acc[7] = b1.w;

#pragma unroll
  for (int dy = -1; dy <= 1; ++dy) {
    int yy = y + dy;
    if (yy < 0 || yy > 13) continue;
#pragma unroll
    for (int dx = -1; dx <= 1; ++dx) {
      int xx = x + dx;
      if (xx < 0 || xx > 13) continue;
      int key = 1 + yy * 14 + xx;
      s16x8 v8 = *(const s16x8*)(vrow + (size_t)key * 64);
      int tap = (dy + 1) * 3 + (dx + 1);
      const float* wrow = wT + tap * 768 + c0;
      float4 w0 = *(const float4*)(wrow);
      float4 w1 = *(const float4*)(wrow + 4);
      acc[0] += w0.x * bf2f(v8[0]);
      acc[1] += w0.y * bf2f(v8[1]);
      acc[2] += w0.z * bf2f(v8[2]);
      acc[3] += w0.w * bf2f(v8[3]);
      acc[4] += w1.x * bf2f(v8[4]);
      acc[5] += w1.y * bf2f(v8[5]);
      acc[6] += w1.z * bf2f(v8[6]);
      acc[7] += w1.w * bf2f(v8[7]);
    }
  }

  size_t ao = ((size_t)b * 197 + (1 + p)) * 768 + c0;
  s16x8 a8 = *(const s16x8*)(aout + ao);
  s16x8 o8;
#pragma unroll
  for (int j = 0; j < 8; ++j) o8[j] = f2bf(bf2f(a8[j]) + acc[j]);
  *(s16x8*)(aout + ao) = o8;
}

// ---------------- launch ----------------

extern "C" void kernel_launch(void* const* d_in, const int* in_sizes, int n_in,
                              void* d_out, int out_size, void* d_ws, size_t ws_size,
                              hipStream_t stream) {
  const float* x     = (const float*)d_in[0];
  const float* Wqkv  = (const float*)d_in[1];
  const float* bqkv  = (const float*)d_in[2];
  const float* Wproj = (const float*)d_in[3];
  const float* bproj = (const float*)d_in[4];
  const float* dwcw  = (const float*)d_in[5];
  const float* dwcb  = (const float*)d_in[6];
  float* out = (float*)d_out;

  const size_t XE = (size_t)50432 * 768;  // 38,731,776 elems
  short* ws     = (short*)d_ws;
  short* xbf    = ws;
  short* wqkvT  = xbf + XE;
  short* wprojT = wqkvT + (size_t)2304 * 768;
  short* qarr   = wprojT + (size_t)768 * 768;
  short* karr   = qarr + XE;
  short* varr   = karr + XE;
  short* aoutb  = xbf;               // reuse x_bf space (dead after gemm_qkv)
  float* wT     = (float*)wqkvT;     // reuse Wqkv^T space (dead after gemm_qkv)

  static bool attr_set = false;
  if (!attr_set) {
    hipFuncSetAttribute((const void*)gemm_qkv256, hipFuncAttributeMaxDynamicSharedMemorySize, 131072);
    hipFuncSetAttribute((const void*)gemm_proj256, hipFuncAttributeMaxDynamicSharedMemorySize, 131072);
    attr_set = true;
  }

  f32_to_bf16_k<<<(int)((XE / 4 + 255) / 256), 256, 0, stream>>>(x, xbf, (int)(XE / 4));
  transpose_bf16_k<<<(2304 * 768 + 255) / 256, 256, 0, stream>>>(Wqkv, wqkvT, 768, 2304);
  transpose_bf16_k<<<(768 * 768 + 255) / 256, 256, 0, stream>>>(Wproj, wprojT, 768, 768);
  gemm_qkv256<<<197 * 9, 512, 131072, stream>>>(xbf, wqkvT, bqkv, qarr, karr, varr);
  transpose_dwc_k<<<27, 256, 0, stream>>>(dwcw, wT);
  attn_fused<<<3072, 256, 0, stream>>>(qarr, karr, varr, aoutb);
  dwconv_add_k<<<(256 * 196 * 96) / 256, 256, 0, stream>>>(varr, wT, dwcb, aoutb);
  gemm_proj256<<<197 * 3, 512, 131072, stream>>>(aoutb, wprojT, bproj, out);
}